// Round 1
// 220.250 us; speedup vs baseline: 1.0320x; 1.0320x over previous
//
#include <hip/hip_runtime.h>
#include <math.h>

#define CC 128
#define HH 32
#define WW 32
#define HW (HH*WW)
#define PP (CC*HW)          // 131072 per level (2^17)
#define NL 3
#define NP (NL*PP)          // 393216 total keypoints
#define PREP_BLOCKS (NP/256)    // 1536; 512 per level
#define TRANS_BLOCKS (NL*4*32)  // 384: per level, 4 c-tiles x 32 pix-tiles of 32x32
#define DESC_BLOCKS (NP/64)     // 6144; 64 rows per block

// d_out layout (floats), concat in return order
#define KP_OFF   0                    // [NP,2]
#define DESC_OFF (NP*2)               // [NP,128]
#define SC_OFF   (DESC_OFF + (size_t)NP*CC) // [NP]
#define MK_OFF   (SC_OFF + NP)        // [NP]

// ws layout (floats)
#define WS_PK   ((size_t)0)           // float2 {ki,kj} per row: 2*NP
#define WS_SM   ((size_t)2*NP)        // masked score per row: NP  (sm!=0 <=> mask)
#define WS_FT   ((size_t)3*NP)        // transposed features, [level][H*W][C]: NP
#define WS_PART ((size_t)4*NP)        // per-block partial sumsq: PREP_BLOCKS

typedef float f32x4 __attribute__((ext_vector_type(4)));

// Fused: blocks [0,PREP_BLOCKS) localization; rest: tiled transpose.
__global__ __launch_bounds__(256) void prep_kernel(
    const float* __restrict__ f0, const float* __restrict__ f1, const float* __restrict__ f2,
    const float* __restrict__ s0, const float* __restrict__ s1, const float* __restrict__ s2,
    float* __restrict__ out, float* __restrict__ ws)
{
    __shared__ float lds_buf[32*33];   // transpose tile / stencil tile (aliased)
    __shared__ float redbuf[4];

    if (blockIdx.x >= PREP_BLOCKS) {
        // ---- tiled transpose: 32 channels x 32 pixels per block ----
        const int b = blockIdx.x - PREP_BLOCKS;     // 0..383
        const int level = b >> 7;
        const int t = b & 127;
        const int c0 = (t >> 5) << 5;
        const int p0 = (t & 31) << 5;
        const float* __restrict__ f = (level == 0) ? f0 : (level == 1) ? f1 : f2;
        const int pj  = threadIdx.x & 31;
        const int ci4 = threadIdx.x >> 5;
        #pragma unroll
        for (int k = 0; k < 4; ++k) {
            const int ci = ci4 + (k << 3);
            lds_buf[ci*33 + pj] = f[(size_t)(c0 + ci)*HW + p0 + pj];
        }
        __syncthreads();
        float* __restrict__ ftl = ws + WS_FT + (size_t)level*PP;
        #pragma unroll
        for (int k = 0; k < 4; ++k) {
            const int ri = ci4 + (k << 3);
            ftl[(size_t)(p0 + ri)*CC + c0 + pj] = lds_buf[pj*33 + ri];
        }
        return;
    }

    // ---- localization: block covers 8 rows of one channel of one level ----
    const int g0 = blockIdx.x * 256;
    const int level = g0 >> 17;                        // uniform per block
    const int p0b = g0 & (PP - 1);
    const int c   = p0b >> 10;
    const int r0  = (p0b & 1023) >> 5;                 // 0, 8, 16, 24
    const float* __restrict__ f  = (level == 0) ? f0 : (level == 1) ? f1 : f2;
    const float* __restrict__ scp = (level == 0) ? s0 : (level == 1) ? s1 : s2;
    const float* __restrict__ fb = f + (c << 10);

    // branch-free stencil: stage rows r0-1..r0+8 into zero-padded LDS tile [10][34]
    float (* __restrict__ tile)[34] = (float (*)[34])lds_buf;
    if (threadIdx.x < 20) {
        tile[threadIdx.x >> 1][(threadIdx.x & 1) * 33] = 0.0f;   // border columns
    }
    for (int idx = threadIdx.x; idx < 320; idx += 256) {
        const int rr = idx >> 5;            // 0..9
        const int jj = idx & 31;
        const int gr = r0 + rr - 1;
        tile[rr][jj + 1] = (gr >= 0 && gr < HH) ? fb[gr*WW + jj] : 0.0f;
    }
    __syncthreads();

    const int g  = g0 + threadIdx.x;
    const int il = (threadIdx.x >> 5) + 1;             // local row in tile
    const int j  = threadIdx.x & 31;
    const int i  = r0 + (threadIdx.x >> 5);

    const float fc  = tile[il    ][j + 1];
    const float fN  = tile[il - 1][j + 1];
    const float fS  = tile[il + 1][j + 1];
    const float fWv = tile[il    ][j    ];
    const float fE  = tile[il    ][j + 2];
    const float fNW = tile[il - 1][j    ];
    const float fNE = tile[il - 1][j + 2];
    const float fSW = tile[il + 1][j    ];
    const float fSE = tile[il + 1][j + 2];

    // Replicate numpy fp32 IEEE evaluation exactly (no FMA contraction).
    const float di  = __fmul_rn(0.5f, __fsub_rn(fS, fN));
    const float dj  = __fmul_rn(0.5f, __fsub_rn(fE, fWv));
    const float dii = __fadd_rn(__fsub_rn(fS, __fmul_rn(2.0f, fc)), fN);
    const float djj = __fadd_rn(__fsub_rn(fE, __fmul_rn(2.0f, fc)), fWv);
    const float dij = __fmul_rn(0.25f, __fadd_rn(__fsub_rn(__fsub_rn(fNW, fNE), fSW), fSE));

    const float det = __fsub_rn(__fmul_rn(dii, djj), __fmul_rn(dij, dij));
    const bool det_ok = fabsf(det) > 1e-10f;
    const float det_s = det_ok ? det : 1.0f;
    const float t1 = __fsub_rn(__fmul_rn(djj, di), __fmul_rn(dij, dj));
    const float disp_i = __fdiv_rn(-t1, det_s);
    const float t2 = __fadd_rn(-__fmul_rn(dij, di), __fmul_rn(dii, dj));
    const float disp_j = __fdiv_rn(-t2, det_s);
    const bool disp_ok = det_ok && (fabsf(disp_i) < 0.5f) && (fabsf(disp_j) < 0.5f);

    const float sraw = scp[p0b + threadIdx.x];
    const float sth = (sraw < 0.5f) ? 0.0f : sraw;
    const bool det_mask = (sth != 0.0f);

    const float ki = __fadd_rn(disp_ok ? disp_i : 0.0f, (float)i);
    const float kj = __fadd_rn(disp_ok ? disp_j : 0.0f, (float)j);
    const float i0 = floorf(ki), i1 = ceilf(ki);
    const float j0 = floorf(kj), j1 = ceilf(kj);
    const bool in_b = (i0 >= 0.0f) && (i1 <= (float)(HH-1)) && (j0 >= 0.0f) && (j1 <= (float)(WW-1));
    const bool mask = det_mask && disp_ok && in_b;
    const float mf = mask ? 1.0f : 0.0f;

    float2 kpv;
    kpv.x = mask ? __fadd_rn(__fmul_rn(ki, 16.0f), 7.5f) : 0.0f;
    kpv.y = mask ? __fadd_rn(__fmul_rn(kj, 16.0f), 7.5f) : 0.0f;
    *(float2*)(out + KP_OFF + 2*(size_t)g) = kpv;
    out[MK_OFF + g] = mf;

    const float sm = mask ? sth : 0.0f;
    ws[WS_SM + g] = sm;

    float2 pk; pk.x = ki; pk.y = kj;
    *(float2*)(ws + WS_PK + 2*(size_t)g) = pk;

    // per-block partial sumsq for the score denominators
    const int lane = threadIdx.x & 63;
    const int wid  = threadIdx.x >> 6;
    float v = __fmul_rn(sm, sm);
    #pragma unroll
    for (int off = 32; off > 0; off >>= 1) v += __shfl_xor(v, off);
    if (lane == 0) redbuf[wid] = v;
    __syncthreads();
    if (threadIdx.x == 0)
        ws[WS_PART + blockIdx.x] = redbuf[0] + redbuf[1] + redbuf[2] + redbuf[3];
}

// Fused second stage: ONE sequential pass over all descriptor rows.
// Block b owns rows [b*64, b*64+64): per row, either a nontemporal 512B zero
// store or inline bilinear gather + normalize + nontemporal 512B store.
// Blocks [0, PREP_BLOCKS) additionally reduce the score denominator for their
// level and write 256 normalized scores each.
__global__ __launch_bounds__(256) void desc_kernel(const float* __restrict__ ws, float* __restrict__ out)
{
    __shared__ float smv[64];
    __shared__ float red[4];
    __shared__ float sden_sh;

    const int b = blockIdx.x;

    // stage this block's 64 row-scores (the zero/compute decision values)
    if (threadIdx.x < 64) smv[threadIdx.x] = ws[WS_SM + b*64 + threadIdx.x];

    if (b < PREP_BLOCKS) {
        // ---- score denominator for this block's level + 256 score writes ----
        const int l = b >> 9;                            // 512 prep blocks per level
        const float* __restrict__ part = ws + WS_PART + l*512;
        float v = part[threadIdx.x] + part[threadIdx.x + 256];
        #pragma unroll
        for (int off = 32; off > 0; off >>= 1) v += __shfl_xor(v, off);
        const int wid  = threadIdx.x >> 6;
        const int lane = threadIdx.x & 63;
        if (lane == 0) red[wid] = v;
        __syncthreads();
        if (threadIdx.x == 0)
            sden_sh = fmaxf(__fsqrt_rn(red[0] + red[1] + red[2] + red[3]), 1e-12f);
        __syncthreads();
        const int idx = b*256 + threadIdx.x;
        const float s = ws[WS_SM + idx];
        out[SC_OFF + idx] = __fdiv_rn(s, sden_sh);
    }
    __syncthreads();

    const int sub    = threadIdx.x >> 5;
    const int lane32 = threadIdx.x & 31;
    const f32x4 z4 = {0.0f, 0.0f, 0.0f, 0.0f};

    #pragma unroll
    for (int k = 0; k < 8; ++k) {
        const int g = b*64 + k*8 + sub;
        const float sm = smv[k*8 + sub];
        f32x4* __restrict__ dst = (f32x4*)(out + DESC_OFF + (size_t)g * CC) + lane32;
        if (sm == 0.0f) {
            __builtin_nontemporal_store(z4, dst);
        } else {
            const int level = g >> 17;
            const float2 pk = *(const float2*)(ws + WS_PK + 2*(size_t)g);
            const float ki = pk.x;
            const float kj = pk.y;
            const float i0 = floorf(ki), i1 = ceilf(ki);
            const float j0 = floorf(kj), j1 = ceilf(kj);
            const int i0c = (int)i0, i1c = (int)i1;
            const int j0c = (int)j0, j1c = (int)j1;       // masked => in-bounds
            const float di_ = ki - i0;
            const float dj_ = kj - j0;
            const float wtl = (1.0f - di_) * (1.0f - dj_);
            const float wtr = (1.0f - di_) * dj_;
            const float wbl = di_ * (1.0f - dj_);
            const float wbr = di_ * dj_;

            const float* __restrict__ ft = ws + WS_FT + (size_t)level * PP;
            const f32x4 tl = *((const f32x4*)(ft + ((size_t)(i0c*WW + j0c)) * CC) + lane32);
            const f32x4 tr = *((const f32x4*)(ft + ((size_t)(i0c*WW + j1c)) * CC) + lane32);
            const f32x4 bl = *((const f32x4*)(ft + ((size_t)(i1c*WW + j0c)) * CC) + lane32);
            const f32x4 br = *((const f32x4*)(ft + ((size_t)(i1c*WW + j1c)) * CC) + lane32);

            f32x4 d;
            d.x = wtl*tl.x + wtr*tr.x + wbl*bl.x + wbr*br.x;
            d.y = wtl*tl.y + wtr*tr.y + wbl*bl.y + wbr*br.y;
            d.z = wtl*tl.z + wtr*tr.z + wbl*bl.z + wbr*br.z;
            d.w = wtl*tl.w + wtr*tr.w + wbl*bl.w + wbr*br.w;

            float ss = d.x*d.x + d.y*d.y + d.z*d.z + d.w*d.w;
            #pragma unroll
            for (int off = 16; off > 0; off >>= 1) ss += __shfl_xor(ss, off);
            const float denom = fmaxf(sqrtf(ss), 1e-12f);
            d.x = __fdiv_rn(d.x, denom);
            d.y = __fdiv_rn(d.y, denom);
            d.z = __fdiv_rn(d.z, denom);
            d.w = __fdiv_rn(d.w, denom);

            __builtin_nontemporal_store(d, dst);
        }
    }
}

extern "C" void kernel_launch(void* const* d_in, const int* in_sizes, int n_in,
                              void* d_out, int out_size, void* d_ws, size_t ws_size,
                              hipStream_t stream) {
    (void)in_sizes; (void)n_in; (void)out_size; (void)ws_size;
    const float* f0 = (const float*)d_in[0];
    const float* f1 = (const float*)d_in[1];
    const float* f2 = (const float*)d_in[2];
    const float* s0 = (const float*)d_in[3];
    const float* s1 = (const float*)d_in[4];
    const float* s2 = (const float*)d_in[5];
    float* out = (float*)d_out;
    float* ws  = (float*)d_ws;

    prep_kernel<<<PREP_BLOCKS + TRANS_BLOCKS, 256, 0, stream>>>(f0, f1, f2, s0, s1, s2, out, ws);
    desc_kernel<<<DESC_BLOCKS, 256, 0, stream>>>(ws, out);
}

// Round 2
// 220.140 us; speedup vs baseline: 1.0325x; 1.0005x over previous
//
#include <hip/hip_runtime.h>
#include <math.h>

#define CC 128
#define HH 32
#define WW 32
#define HW (HH*WW)
#define PP (CC*HW)          // 131072 per level (2^17)
#define NL 3
#define NP (NL*PP)          // 393216 total keypoints
#define PREP_BLOCKS (NP/256)    // 1536; 512 per level
#define TRANS_BLOCKS (NL*4*32)  // 384: per level, 4 c-tiles x 32 pix-tiles of 32x32
#define DESC_ROWS 128
#define DESC_BLOCKS (NP/DESC_ROWS)  // 3072

// d_out layout (floats), concat in return order
#define KP_OFF   0                    // [NP,2]
#define DESC_OFF (NP*2)               // [NP,128]
#define SC_OFF   (DESC_OFF + (size_t)NP*CC) // [NP]
#define MK_OFF   (SC_OFF + NP)        // [NP]

// ws layout (floats)
#define WS_PKS  ((size_t)0)           // float4 {ki,kj,sm,0} per row: 4*NP
#define WS_SM   ((size_t)4*NP)        // masked score per row: NP  (for score pass)
#define WS_FT   ((size_t)5*NP)        // transposed features, [level][H*W][C]: NP
#define WS_PART ((size_t)6*NP)        // per-block partial sumsq: PREP_BLOCKS

typedef float f32x4 __attribute__((ext_vector_type(4)));

// Fused: blocks [0,PREP_BLOCKS) localization; rest: tiled transpose.
__global__ __launch_bounds__(256) void prep_kernel(
    const float* __restrict__ f0, const float* __restrict__ f1, const float* __restrict__ f2,
    const float* __restrict__ s0, const float* __restrict__ s1, const float* __restrict__ s2,
    float* __restrict__ out, float* __restrict__ ws)
{
    __shared__ float lds_buf[32*33];   // transpose tile / stencil tile (aliased)
    __shared__ float redbuf[4];

    if (blockIdx.x >= PREP_BLOCKS) {
        // ---- tiled transpose: 32 channels x 32 pixels per block ----
        const int b = blockIdx.x - PREP_BLOCKS;     // 0..383
        const int level = b >> 7;
        const int t = b & 127;
        const int c0 = (t >> 5) << 5;
        const int p0 = (t & 31) << 5;
        const float* __restrict__ f = (level == 0) ? f0 : (level == 1) ? f1 : f2;
        const int pj  = threadIdx.x & 31;
        const int ci4 = threadIdx.x >> 5;
        #pragma unroll
        for (int k = 0; k < 4; ++k) {
            const int ci = ci4 + (k << 3);
            lds_buf[ci*33 + pj] = f[(size_t)(c0 + ci)*HW + p0 + pj];
        }
        __syncthreads();
        float* __restrict__ ftl = ws + WS_FT + (size_t)level*PP;
        #pragma unroll
        for (int k = 0; k < 4; ++k) {
            const int ri = ci4 + (k << 3);
            ftl[(size_t)(p0 + ri)*CC + c0 + pj] = lds_buf[pj*33 + ri];
        }
        return;
    }

    // ---- localization: block covers 8 rows of one channel of one level ----
    const int g0 = blockIdx.x * 256;
    const int level = g0 >> 17;                        // uniform per block
    const int p0b = g0 & (PP - 1);
    const int c   = p0b >> 10;
    const int r0  = (p0b & 1023) >> 5;                 // 0, 8, 16, 24
    const float* __restrict__ f  = (level == 0) ? f0 : (level == 1) ? f1 : f2;
    const float* __restrict__ scp = (level == 0) ? s0 : (level == 1) ? s1 : s2;
    const float* __restrict__ fb = f + (c << 10);

    // branch-free stencil: stage rows r0-1..r0+8 into zero-padded LDS tile [10][34]
    float (* __restrict__ tile)[34] = (float (*)[34])lds_buf;
    if (threadIdx.x < 20) {
        tile[threadIdx.x >> 1][(threadIdx.x & 1) * 33] = 0.0f;   // border columns
    }
    for (int idx = threadIdx.x; idx < 320; idx += 256) {
        const int rr = idx >> 5;            // 0..9
        const int jj = idx & 31;
        const int gr = r0 + rr - 1;
        tile[rr][jj + 1] = (gr >= 0 && gr < HH) ? fb[gr*WW + jj] : 0.0f;
    }
    __syncthreads();

    const int g  = g0 + threadIdx.x;
    const int il = (threadIdx.x >> 5) + 1;             // local row in tile
    const int j  = threadIdx.x & 31;
    const int i  = r0 + (threadIdx.x >> 5);

    const float fc  = tile[il    ][j + 1];
    const float fN  = tile[il - 1][j + 1];
    const float fS  = tile[il + 1][j + 1];
    const float fWv = tile[il    ][j    ];
    const float fE  = tile[il    ][j + 2];
    const float fNW = tile[il - 1][j    ];
    const float fNE = tile[il - 1][j + 2];
    const float fSW = tile[il + 1][j    ];
    const float fSE = tile[il + 1][j + 2];

    // Replicate numpy fp32 IEEE evaluation exactly (no FMA contraction).
    const float di  = __fmul_rn(0.5f, __fsub_rn(fS, fN));
    const float dj  = __fmul_rn(0.5f, __fsub_rn(fE, fWv));
    const float dii = __fadd_rn(__fsub_rn(fS, __fmul_rn(2.0f, fc)), fN);
    const float djj = __fadd_rn(__fsub_rn(fE, __fmul_rn(2.0f, fc)), fWv);
    const float dij = __fmul_rn(0.25f, __fadd_rn(__fsub_rn(__fsub_rn(fNW, fNE), fSW), fSE));

    const float det = __fsub_rn(__fmul_rn(dii, djj), __fmul_rn(dij, dij));
    const bool det_ok = fabsf(det) > 1e-10f;
    const float det_s = det_ok ? det : 1.0f;
    const float t1 = __fsub_rn(__fmul_rn(djj, di), __fmul_rn(dij, dj));
    const float disp_i = __fdiv_rn(-t1, det_s);
    const float t2 = __fadd_rn(-__fmul_rn(dij, di), __fmul_rn(dii, dj));
    const float disp_j = __fdiv_rn(-t2, det_s);
    const bool disp_ok = det_ok && (fabsf(disp_i) < 0.5f) && (fabsf(disp_j) < 0.5f);

    const float sraw = scp[p0b + threadIdx.x];
    const float sth = (sraw < 0.5f) ? 0.0f : sraw;
    const bool det_mask = (sth != 0.0f);

    const float ki = __fadd_rn(disp_ok ? disp_i : 0.0f, (float)i);
    const float kj = __fadd_rn(disp_ok ? disp_j : 0.0f, (float)j);
    const float i0 = floorf(ki), i1 = ceilf(ki);
    const float j0 = floorf(kj), j1 = ceilf(kj);
    const bool in_b = (i0 >= 0.0f) && (i1 <= (float)(HH-1)) && (j0 >= 0.0f) && (j1 <= (float)(WW-1));
    const bool mask = det_mask && disp_ok && in_b;
    const float mf = mask ? 1.0f : 0.0f;

    float2 kpv;
    kpv.x = mask ? __fadd_rn(__fmul_rn(ki, 16.0f), 7.5f) : 0.0f;
    kpv.y = mask ? __fadd_rn(__fmul_rn(kj, 16.0f), 7.5f) : 0.0f;
    *(float2*)(out + KP_OFF + 2*(size_t)g) = kpv;
    out[MK_OFF + g] = mf;

    const float sm = mask ? sth : 0.0f;
    ws[WS_SM + g] = sm;

    // packed per-row state for desc: one 16B load per row downstream
    f32x4 pks;
    pks.x = ki; pks.y = kj; pks.z = sm; pks.w = 0.0f;
    *(f32x4*)(ws + WS_PKS + 4*(size_t)g) = pks;

    // per-block partial sumsq for the score denominators
    const int lane = threadIdx.x & 63;
    const int wid  = threadIdx.x >> 6;
    float v = __fmul_rn(sm, sm);
    #pragma unroll
    for (int off = 32; off > 0; off >>= 1) v += __shfl_xor(v, off);
    if (lane == 0) redbuf[wid] = v;
    __syncthreads();
    if (threadIdx.x == 0)
        ws[WS_PART + blockIdx.x] = redbuf[0] + redbuf[1] + redbuf[2] + redbuf[3];
}

// Fused second stage: ONE sequential pass over all descriptor rows.
// Block b owns rows [b*128, b*128+128): per row, either a nontemporal 512B zero
// store or inline bilinear gather + normalize + nontemporal 512B store.
// Per-row state {ki,kj,sm} staged as one coalesced float4 read into LDS.
// Blocks [0, PREP_BLOCKS) additionally reduce the score denominator for their
// level and write 256 normalized scores each.
__global__ __launch_bounds__(256) void desc_kernel(const float* __restrict__ ws, float* __restrict__ out)
{
    __shared__ f32x4 pks_sh[DESC_ROWS];
    __shared__ float red[4];
    __shared__ float sden_sh;

    const int b = blockIdx.x;

    // stage this block's 128 rows of packed state (2KB, fully coalesced)
    if (threadIdx.x < DESC_ROWS)
        pks_sh[threadIdx.x] = *((const f32x4*)(ws + WS_PKS) + b*DESC_ROWS + threadIdx.x);

    if (b < PREP_BLOCKS) {
        // ---- score denominator for this block's level + 256 score writes ----
        const int l = b >> 9;                            // 512 prep blocks per level
        const float* __restrict__ part = ws + WS_PART + l*512;
        float v = part[threadIdx.x] + part[threadIdx.x + 256];
        #pragma unroll
        for (int off = 32; off > 0; off >>= 1) v += __shfl_xor(v, off);
        const int wid  = threadIdx.x >> 6;
        const int lane = threadIdx.x & 63;
        if (lane == 0) red[wid] = v;
        __syncthreads();
        if (threadIdx.x == 0)
            sden_sh = fmaxf(__fsqrt_rn(red[0] + red[1] + red[2] + red[3]), 1e-12f);
        __syncthreads();
        const int idx = b*256 + threadIdx.x;
        const float s = ws[WS_SM + idx];
        out[SC_OFF + idx] = __fdiv_rn(s, sden_sh);
    }
    __syncthreads();

    const int sub    = threadIdx.x >> 5;
    const int lane32 = threadIdx.x & 31;
    const f32x4 z4 = {0.0f, 0.0f, 0.0f, 0.0f};

    #pragma unroll
    for (int k = 0; k < DESC_ROWS/8; ++k) {
        const int r = k*8 + sub;
        const int g = b*DESC_ROWS + r;
        const f32x4 pks = pks_sh[r];                  // broadcast within group
        f32x4* __restrict__ dst = (f32x4*)(out + DESC_OFF + (size_t)g * CC) + lane32;
        if (pks.z == 0.0f) {
            __builtin_nontemporal_store(z4, dst);
        } else {
            const int level = g >> 17;
            const float ki = pks.x;
            const float kj = pks.y;
            const float i0 = floorf(ki), i1 = ceilf(ki);
            const float j0 = floorf(kj), j1 = ceilf(kj);
            const int i0c = (int)i0, i1c = (int)i1;
            const int j0c = (int)j0, j1c = (int)j1;       // masked => in-bounds
            const float di_ = ki - i0;
            const float dj_ = kj - j0;
            const float wtl = (1.0f - di_) * (1.0f - dj_);
            const float wtr = (1.0f - di_) * dj_;
            const float wbl = di_ * (1.0f - dj_);
            const float wbr = di_ * dj_;

            const float* __restrict__ ft = ws + WS_FT + (size_t)level * PP;
            const f32x4 tl = *((const f32x4*)(ft + ((size_t)(i0c*WW + j0c)) * CC) + lane32);
            const f32x4 tr = *((const f32x4*)(ft + ((size_t)(i0c*WW + j1c)) * CC) + lane32);
            const f32x4 bl = *((const f32x4*)(ft + ((size_t)(i1c*WW + j0c)) * CC) + lane32);
            const f32x4 br = *((const f32x4*)(ft + ((size_t)(i1c*WW + j1c)) * CC) + lane32);

            f32x4 d;
            d.x = wtl*tl.x + wtr*tr.x + wbl*bl.x + wbr*br.x;
            d.y = wtl*tl.y + wtr*tr.y + wbl*bl.y + wbr*br.y;
            d.z = wtl*tl.z + wtr*tr.z + wbl*bl.z + wbr*br.z;
            d.w = wtl*tl.w + wtr*tr.w + wbl*bl.w + wbr*br.w;

            float ss = d.x*d.x + d.y*d.y + d.z*d.z + d.w*d.w;
            #pragma unroll
            for (int off = 16; off > 0; off >>= 1) ss += __shfl_xor(ss, off);
            const float denom = fmaxf(sqrtf(ss), 1e-12f);
            d.x = __fdiv_rn(d.x, denom);
            d.y = __fdiv_rn(d.y, denom);
            d.z = __fdiv_rn(d.z, denom);
            d.w = __fdiv_rn(d.w, denom);

            __builtin_nontemporal_store(d, dst);
        }
    }
}

extern "C" void kernel_launch(void* const* d_in, const int* in_sizes, int n_in,
                              void* d_out, int out_size, void* d_ws, size_t ws_size,
                              hipStream_t stream) {
    (void)in_sizes; (void)n_in; (void)out_size; (void)ws_size;
    const float* f0 = (const float*)d_in[0];
    const float* f1 = (const float*)d_in[1];
    const float* f2 = (const float*)d_in[2];
    const float* s0 = (const float*)d_in[3];
    const float* s1 = (const float*)d_in[4];
    const float* s2 = (const float*)d_in[5];
    float* out = (float*)d_out;
    float* ws  = (float*)d_ws;

    prep_kernel<<<PREP_BLOCKS + TRANS_BLOCKS, 256, 0, stream>>>(f0, f1, f2, s0, s1, s2, out, ws);
    desc_kernel<<<DESC_BLOCKS, 256, 0, stream>>>(ws, out);
}